// Round 1
// baseline (492.746 us; speedup 1.0000x reference)
//
#include <hip/hip_runtime.h>
#include <math.h>

#define BATCH   4
#define N1      2048
#define N2      8192
#define F       256
#define NTOT1   (BATCH * N1)    // 8192
#define NTOT2   (BATCH * N2)    // 32768
#define BN_EPS  1e-5f

// ---------------- zero the stats accumulators (ws is poisoned 0xAA) ----------
__global__ void zero_stats_kernel(float* sums) {
    int t = threadIdx.x;
    #pragma unroll
    for (int i = 0; i < 4; ++i) sums[t + 256 * i] = 0.0f;
}

// ---------------- GEMM: H[M,256] = X[M,256] @ W[256,256] + bias --------------
// block = 256 threads; tile = 32 rows x 256 cols.
// thread (cg = t&63, rg = t>>6): cols {cg + 64j, j=0..3}, rows {rg*8 + rr, rr=0..7}
__global__ __launch_bounds__(256) void gemm_kernel(const float* __restrict__ X,
                                                   const float* __restrict__ W,
                                                   const float* __restrict__ bias,
                                                   float* __restrict__ H) {
    __shared__ float xs[32][256];
    const int row0 = blockIdx.x * 32;
    const int t  = threadIdx.x;
    const int cg = t & 63;
    const int rg = t >> 6;

    // stage the 32x256 X tile (coalesced: thread t loads col t of each row)
    #pragma unroll
    for (int s = 0; s < 32; ++s)
        xs[s][t] = X[(size_t)(row0 + s) * F + t];
    __syncthreads();

    float acc[4][8];
    #pragma unroll
    for (int j = 0; j < 4; ++j)
        #pragma unroll
        for (int rr = 0; rr < 8; ++rr) acc[j][rr] = 0.0f;

    for (int k = 0; k < 256; k += 4) {
        float wv[4][4];   // [kk][j]
        #pragma unroll
        for (int kk = 0; kk < 4; ++kk)
            #pragma unroll
            for (int j = 0; j < 4; ++j)
                wv[kk][j] = W[(size_t)(k + kk) * F + cg + 64 * j];
        #pragma unroll
        for (int rr = 0; rr < 8; ++rr) {
            const float4 x4 = *(const float4*)&xs[rg * 8 + rr][k];
            #pragma unroll
            for (int j = 0; j < 4; ++j) {
                acc[j][rr] = fmaf(x4.x, wv[0][j], acc[j][rr]);
                acc[j][rr] = fmaf(x4.y, wv[1][j], acc[j][rr]);
                acc[j][rr] = fmaf(x4.z, wv[2][j], acc[j][rr]);
                acc[j][rr] = fmaf(x4.w, wv[3][j], acc[j][rr]);
            }
        }
    }

    float bv[4];
    #pragma unroll
    for (int j = 0; j < 4; ++j) bv[j] = bias[cg + 64 * j];
    #pragma unroll
    for (int rr = 0; rr < 8; ++rr)
        #pragma unroll
        for (int j = 0; j < 4; ++j)
            H[(size_t)(row0 + rg * 8 + rr) * F + cg + 64 * j] = acc[j][rr] + bv[j];
}

// ---------------- per-feature sum & sumsq (for BN batch stats) ---------------
__global__ __launch_bounds__(256) void stats_kernel(const float* __restrict__ H,
                                                    int rows_per_block,
                                                    float* __restrict__ sum,
                                                    float* __restrict__ sumsq) {
    const int t = threadIdx.x;
    const size_t base = (size_t)blockIdx.x * rows_per_block * F;
    float s = 0.0f, q = 0.0f;
    for (int r = 0; r < rows_per_block; ++r) {
        const float v = H[base + (size_t)r * F + t];
        s += v;
        q = fmaf(v, v, q);
    }
    atomicAdd(&sum[t], s);
    atomicAdd(&sumsq[t], q);
}

// ---------------- fold BN into scale/shift: out = s*h + t --------------------
// sums layout: [sum1 | sq1 | sum2 | sq2], ss layout: [s1 | t1 | s2 | t2]
__global__ void finalize_kernel(const float* __restrict__ sums,
                                const float* __restrict__ g1, const float* __restrict__ be1,
                                const float* __restrict__ g2, const float* __restrict__ be2,
                                float* __restrict__ ss) {
    const int t = threadIdx.x;
    const float m1 = sums[t] * (1.0f / (float)NTOT1);
    const float v1 = sums[256 + t] * (1.0f / (float)NTOT1) - m1 * m1;
    const float s1 = g1[t] * rsqrtf(v1 + BN_EPS);
    ss[t]       = s1;
    ss[256 + t] = be1[t] - m1 * s1;
    const float m2 = sums[512 + t] * (1.0f / (float)NTOT2);
    const float v2 = sums[768 + t] * (1.0f / (float)NTOT2) - m2 * m2;
    const float s2 = g2[t] * rsqrtf(v2 + BN_EPS);
    ss[512 + t] = s2;
    ss[768 + t] = be2[t] - m2 * s2;
}

// ---------------- brute-force kNN (K=3) within each batch --------------------
// one thread per p2 point; p1[b] staged in LDS (SoA, 24 KB)
__global__ __launch_bounds__(256) void knn_kernel(const float* __restrict__ p1,
                                                  const float* __restrict__ p2,
                                                  int* __restrict__ idx_out,
                                                  float* __restrict__ w_out) {
    __shared__ float px[N1], py[N1], pz[N1];
    const int i = blockIdx.x * 256 + threadIdx.x;   // global p2 index
    const int b = i >> 13;                          // i / N2 (N2 = 8192)

    for (int j = threadIdx.x; j < N1; j += 256) {
        const size_t base = (size_t)(b * N1 + j) * 3;
        px[j] = p1[base + 0];
        py[j] = p1[base + 1];
        pz[j] = p1[base + 2];
    }
    __syncthreads();

    const float qx = p2[(size_t)i * 3 + 0];
    const float qy = p2[(size_t)i * 3 + 1];
    const float qz = p2[(size_t)i * 3 + 2];

    float d0 = 1e30f, d1 = 1e30f, d2v = 1e30f;
    int   i0 = 0,     i1 = 0,     i2 = 0;

    for (int j = 0; j < N1; ++j) {
        const float dx = px[j] - qx;
        const float dy = py[j] - qy;
        const float dz = pz[j] - qz;
        float d = dx * dx;
        d = fmaf(dy, dy, d);
        d = fmaf(dz, dz, d);
        if (d < d2v) {
            if (d < d1) {
                d2v = d1; i2 = i1;
                if (d < d0) { d1 = d0; i1 = i0; d0 = d; i0 = j; }
                else        { d1 = d;  i1 = j; }
            } else { d2v = d; i2 = j; }
        }
    }

    const float w0 = 1.0f / fmaxf(d0,  1e-16f);
    const float w1 = 1.0f / fmaxf(d1,  1e-16f);
    const float w2 = 1.0f / fmaxf(d2v, 1e-16f);
    const float inv = 1.0f / (w0 + w1 + w2);

    idx_out[(size_t)i * 3 + 0] = b * N1 + i0;   // global row into h1
    idx_out[(size_t)i * 3 + 1] = b * N1 + i1;
    idx_out[(size_t)i * 3 + 2] = b * N1 + i2;
    w_out[(size_t)i * 3 + 0] = w0 * inv;        // pre-normalized: sums to 1
    w_out[(size_t)i * 3 + 1] = w1 * inv;
    w_out[(size_t)i * 3 + 2] = w2 * inv;
}

// ---------------- interpolate + BN-apply + add + write -----------------------
// out[i,f] = s1[f]*(w0*h1[j0,f]+w1*h1[j1,f]+w2*h1[j2,f]) + t1[f]
//          + s2[f]*h2[i,f] + t2[f]          (valid since w0+w1+w2 == 1)
__global__ __launch_bounds__(256) void interp_kernel(const float* __restrict__ h1,
                                                     const float* __restrict__ h2,
                                                     const int* __restrict__ idx,
                                                     const float* __restrict__ w,
                                                     const float* __restrict__ ss,
                                                     float* __restrict__ out) {
    const int i = blockIdx.x;       // 0..NTOT2-1
    const int t = threadIdx.x;      // feature

    const int   j0 = idx[(size_t)i * 3 + 0];
    const int   j1 = idx[(size_t)i * 3 + 1];
    const int   j2 = idx[(size_t)i * 3 + 2];
    const float w0 = w[(size_t)i * 3 + 0];
    const float w1 = w[(size_t)i * 3 + 1];
    const float w2 = w[(size_t)i * 3 + 2];

    const float s1 = ss[t],       t1 = ss[256 + t];
    const float s2 = ss[512 + t], t2 = ss[768 + t];

    float a = w0 * h1[(size_t)j0 * F + t];
    a = fmaf(w1, h1[(size_t)j1 * F + t], a);
    a = fmaf(w2, h1[(size_t)j2 * F + t], a);

    const float o = fmaf(a, s1, t1) + fmaf(h2[(size_t)i * F + t], s2, t2);
    out[(size_t)i * F + t] = o;
}

// ---------------- passthrough tail: positions_2 + batch_2 --------------------
__global__ __launch_bounds__(256) void tail_kernel(const float* __restrict__ pos2,
                                                   float* __restrict__ out) {
    const int i = blockIdx.x * 256 + threadIdx.x;
    if (i < NTOT2 * 3) out[(size_t)NTOT2 * F + i] = pos2[i];
    if (i < NTOT2)     out[(size_t)NTOT2 * F + NTOT2 * 3 + i] = (float)(i >> 13);
}

// -----------------------------------------------------------------------------
extern "C" void kernel_launch(void* const* d_in, const int* in_sizes, int n_in,
                              void* d_out, int out_size, void* d_ws, size_t ws_size,
                              hipStream_t stream) {
    const float* f1  = (const float*)d_in[0];
    const float* p1  = (const float*)d_in[1];
    const float* f2  = (const float*)d_in[3];
    const float* p2  = (const float*)d_in[4];
    const float* W1  = (const float*)d_in[6];
    const float* b1  = (const float*)d_in[7];
    const float* g1  = (const float*)d_in[8];
    const float* be1 = (const float*)d_in[9];
    const float* W2  = (const float*)d_in[10];
    const float* b2  = (const float*)d_in[11];
    const float* g2  = (const float*)d_in[12];
    const float* be2 = (const float*)d_in[13];

    char* ws = (char*)d_ws;
    float* h1      = (float*)(ws);                              //  8,388,608 B
    float* h2      = (float*)(ws + 8388608);                    // 33,554,432 B
    float* sums    = (float*)(ws + 41943040);                   //  4,096 B
    float* ssbuf   = (float*)(ws + 41947136);                   //  4,096 B
    int*   knn_idx = (int*)  (ws + 41951232);                   //  393,216 B
    float* knn_w   = (float*)(ws + 42344448);                   //  393,216 B
    float* out     = (float*)d_out;

    zero_stats_kernel<<<1, 256, 0, stream>>>(sums);

    gemm_kernel<<<NTOT1 / 32, 256, 0, stream>>>(f1, W1, b1, h1);
    gemm_kernel<<<NTOT2 / 32, 256, 0, stream>>>(f2, W2, b2, h2);

    stats_kernel<<<64,  256, 0, stream>>>(h1, NTOT1 / 64,  sums,       sums + 256);
    stats_kernel<<<256, 256, 0, stream>>>(h2, NTOT2 / 256, sums + 512, sums + 768);

    finalize_kernel<<<1, 256, 0, stream>>>(sums, g1, be1, g2, be2, ssbuf);

    knn_kernel<<<NTOT2 / 256, 256, 0, stream>>>(p1, p2, knn_idx, knn_w);

    interp_kernel<<<NTOT2, 256, 0, stream>>>(h1, h2, knn_idx, knn_w, ssbuf, out);

    tail_kernel<<<(NTOT2 * 3 + 255) / 256, 256, 0, stream>>>(p2, out);
}